// Round 10
// baseline (605.722 us; speedup 1.0000x reference)
//
#include <hip/hip_runtime.h>

#define NN 100000
#define EE 1250000
#define HH 64
#define BB 256
#define CC 2
#define NBLK 391                       // ceil((NN+1)/256)
#define CS ((size_t)(NN + 1) * 8)      // floats per feature-chunk (incl. dummy row NN)
#define GATH_BLK 8192
#define WPC ((GATH_BLK / 8) * 4)       // waves per chunk = 4096
#define GEMM_BLK 2048
#define GEMM_WAVES (GEMM_BLK * 4)
#define NSH 12500                      // nodes per XCD shard (NN/8)
#define CAP 170000                     // bucket capacity (expect 156250, sigma~370)
#define FSB_PER 128                    // fill blocks per shard
#define PRE_PER 49                     // prefill blocks per shard (49*256 >= 12500)
#define CB_BLK ((EE + 1023) / 1024)    // count_bucket blocks (1024 edges each)

typedef int ivec4 __attribute__((ext_vector_type(4)));
typedef int ivec2 __attribute__((ext_vector_type(2)));

// ---------------------------------------------------------------------------
// Index dtype detection (int64 vs int32): int64 values < 2^31 -> odd words 0
// ---------------------------------------------------------------------------
__global__ void detect_i64(const int* __restrict__ raw, int* __restrict__ flag) {
    __shared__ int nonzero;
    if (threadIdx.x == 0) nonzero = 0;
    __syncthreads();
    int any = 0;
#pragma unroll
    for (int i = 0; i < 4; ++i) {
        int idx = 2 * (threadIdx.x + i * 256) + 1;
        if (raw[idx] != 0) any = 1;
    }
    if (any) atomicOr(&nonzero, 1);
    __syncthreads();
    if (threadIdx.x == 0) *flag = nonzero ? 0 : 1;   // 1 => int64
}

// ---------------------------------------------------------------------------
// Pass A: degree count + bucketize edges by dst-shard (8 buckets).
// ---------------------------------------------------------------------------
__global__ __launch_bounds__(256) void count_bucket(
        const int* __restrict__ raw, const int* __restrict__ flag,
        int* __restrict__ degi, int* __restrict__ bfill,
        ivec2* __restrict__ pairs) {
    __shared__ int lh[8];
    __shared__ int lbase[8];
    int tid = threadIdx.x;
    if (tid < 8) lh[tid] = 0;
    __syncthreads();
    int flg = *flag;
    int e0 = blockIdx.x * 1024 + tid;
    int sv[4], dv[4], rk[4], bk[4];
#pragma unroll
    for (int i = 0; i < 4; ++i) {
        int e = e0 + i * 256;
        if (e < EE) {
            int s = flg ? raw[2 * e]        : raw[e];
            int d = flg ? raw[2 * (EE + e)] : raw[EE + e];
            atomicAdd(&degi[d], 1);
            int b = d / NSH;               // const divide -> magic mul
            bk[i] = b;
            rk[i] = atomicAdd(&lh[b], 1);  // local rank (LDS atomic)
            sv[i] = s; dv[i] = d;
        } else {
            bk[i] = -1; sv[i] = 0; dv[i] = 0; rk[i] = 0;
        }
    }
    __syncthreads();
    if (tid < 8) lbase[tid] = atomicAdd(&bfill[tid], lh[tid]);
    __syncthreads();
#pragma unroll
    for (int i = 0; i < 4; ++i) {
        if (bk[i] >= 0) {
            int pos = bk[i] * CAP + lbase[bk[i]] + rk[i];
            ivec2 pr; pr.x = sv[i]; pr.y = dv[i];
            pairs[pos] = pr;
        }
    }
}

// scan over padded degrees pdeg = (deg+16)&~15 (self + dummies, mult of 16)
__global__ __launch_bounds__(256) void scan1(const int* __restrict__ degi,
                                             int* __restrict__ row2,
                                             int* __restrict__ bsum,
                                             float* __restrict__ dinv) {
    __shared__ int s[256];
    int tid = threadIdx.x;
    int n = blockIdx.x * 256 + tid;
    int dg = (n < NN) ? degi[n] : 0;
    int v = (n < NN) ? ((dg + 16) & ~15) : 0;   // pdeg (>= dg+1, mult 16)
    int x = v;
    s[tid] = x;
    __syncthreads();
    for (int off = 1; off < 256; off <<= 1) {
        int t = (tid >= off) ? s[tid - off] : 0;
        __syncthreads();
        x += t;
        s[tid] = x;
        __syncthreads();
    }
    if (n <= NN) row2[n] = x - v;            // exclusive (partial)
    if (n < NN) dinv[n] = rsqrtf((float)dg + 1.0f);
    if (tid == 255) bsum[blockIdx.x] = x;
}

__global__ __launch_bounds__(512) void scan2(int* __restrict__ bsum) {
    __shared__ int s[512];
    int tid = threadIdx.x;
    int v = (tid < NBLK) ? bsum[tid] : 0;
    int x = v;
    s[tid] = x;
    __syncthreads();
    for (int off = 1; off < 512; off <<= 1) {
        int t = (tid >= off) ? s[tid - off] : 0;
        __syncthreads();
        x += t;
        s[tid] = x;
        __syncthreads();
    }
    if (tid < NBLK) bsum[tid] = x - v;
}

__global__ void scan3(int* __restrict__ row2, const int* __restrict__ bsum) {
    int n = blockIdx.x * 256 + threadIdx.x;
    if (n <= NN) row2[n] += bsum[blockIdx.x];
}

// ---------------------------------------------------------------------------
// XCD-sharded prefill: self-slot + padding tail (up to 15 dummies)
// ---------------------------------------------------------------------------
__global__ void prefill_shard(const int* __restrict__ row2, const int* __restrict__ degi,
                              int* __restrict__ esrc2) {
    int shard = blockIdx.x & 7;
    int lb = blockIdx.x >> 3;
    int ln = lb * 256 + threadIdx.x;
    if (ln >= NSH) return;
    int n = shard * NSH + ln;
    int b = row2[n], e = row2[n + 1], dg = degi[n];
    esrc2[b] = n;                                  // self edge
    for (int k = b + 1 + dg; k < e; ++k) esrc2[k] = NN;  // padding -> zero row
}

// ---------------------------------------------------------------------------
// Pass B: per-shard counting-sort fill (bucket + window L2-resident per XCD)
// ---------------------------------------------------------------------------
__global__ __launch_bounds__(256) void fill_shard2(
        const ivec2* __restrict__ pairs, const int* __restrict__ bfill,
        const int* __restrict__ row2, int* __restrict__ fillc,
        int* __restrict__ esrc2) {
    int shard = blockIdx.x & 7;
    int lb = blockIdx.x >> 3;
    int tot = bfill[shard];
    const ivec2* __restrict__ bp = pairs + (size_t)shard * CAP;
    for (int i = lb * 256 + threadIdx.x; i < tot; i += FSB_PER * 256) {
        ivec2 p = bp[i];
        int pos = row2[p.y] + 1 + atomicAdd(&fillc[p.y], 1);
        esrc2[pos] = p.x;
    }
}

// ---------------------------------------------------------------------------
// G = dinv .* (X @ W), chunk-major out [8][NN+1][8]; row NN zeroed.
// ---------------------------------------------------------------------------
template <int IN_ROW>
__global__ __launch_bounds__(256) void gemm_scaled(
        const float* __restrict__ X, const float* __restrict__ W,
        const float* __restrict__ dinv, float* __restrict__ G) {
    int lane = threadIdx.x & 63;
    int gw = (blockIdx.x * 256 + threadIdx.x) >> 6;
    float Wreg[64];
#pragma unroll
    for (int k = 0; k < 64; ++k) Wreg[k] = W[k * 64 + lane];
    int c = lane >> 3, fl = lane & 7;
    for (int n = gw; n <= NN; n += GEMM_WAVES) {
        int nu = __builtin_amdgcn_readfirstlane(n);
        float r = 0.0f;
        if (nu < NN) {
            float a0 = 0.f, a1 = 0.f;
#pragma unroll
            for (int k = 0; k < 64; k += 2) {
                float x0, x1;
                if constexpr (IN_ROW) {
                    x0 = X[(size_t)nu * 64 + k];
                    x1 = X[(size_t)nu * 64 + k + 1];
                } else {
                    x0 = X[(size_t)(k >> 3) * CS + (size_t)nu * 8 + (k & 7)];
                    x1 = X[(size_t)((k + 1) >> 3) * CS + (size_t)nu * 8 + ((k + 1) & 7)];
                }
                a0 = fmaf(x0, Wreg[k], a0);
                a1 = fmaf(x1, Wreg[k + 1], a1);
            }
            r = (a0 + a1) * dinv[nu];
        }
        G[(size_t)c * CS + (size_t)nu * 8 + fl] = r;
    }
}

// ---------------------------------------------------------------------------
// XCD-sharded gather, ONE node per wave: lane = edge_sub(8) x feat(8).
// Per 8 slots: 1 esrc2 request (64 lanes share one 32B line) + 8 G-row
// requests. Segments padded to mult-16 -> 2 independent chains, no bounds
// checks, zero divergence. Dummy slots read the L1-hot zero row NN.
// ---------------------------------------------------------------------------
template <int RELU>
__global__ __launch_bounds__(256) void gather_ef(
        const int* __restrict__ row2, const int* __restrict__ esrc2,
        const float* __restrict__ G, const float* __restrict__ dinv,
        const float* __restrict__ bias, float* __restrict__ Out) {
    int lane = threadIdx.x & 63;
    int fl = lane & 7, eg = lane >> 3;
    int chunk = blockIdx.x & 7;
    int wv = ((blockIdx.x >> 3) << 2) + (threadIdx.x >> 6);
    const float* __restrict__ Gc = G + (size_t)chunk * CS;
    float bv = bias[chunk * 8 + fl];

    for (int n0 = wv; n0 < NN; n0 += WPC) {
        int n = __builtin_amdgcn_readfirstlane(n0);
        int beg = row2[n], end = row2[n + 1];          // s_loads (uniform)
        float aA = 0.f, aB = 0.f;
        for (int j = beg; j < end; j += 16) {
            int sA = esrc2[j + eg];                    // 1 req (32B shared)
            int sB = esrc2[j + 8 + eg];                // 1 req
            aA += Gc[(unsigned)(sA * 8 + fl)];         // 8 req
            aB += Gc[(unsigned)(sB * 8 + fl)];         // 8 req (dummies: hot line)
        }
        float acc = aA + aB;
        acc += __shfl_xor(acc, 8, 64);
        acc += __shfl_xor(acc, 16, 64);
        acc += __shfl_xor(acc, 32, 64);
        float o = fmaf(acc, dinv[n], bv);
        if constexpr (RELU) o = fmaxf(o, 0.f);
        if (lane < 8)
            Out[(size_t)chunk * CS + (size_t)n * 8 + fl] = o;
    }
}

// ---------------------------------------------------------------------------
// Mean pool (batch sorted, chunk-major input) + final linear
// ---------------------------------------------------------------------------
__global__ __launch_bounds__(256) void pool_kernel(
        const float* __restrict__ Hc, const int* __restrict__ braw,
        const int* __restrict__ flag,
        float* __restrict__ pooled, float* __restrict__ cnt) {
    int tid = threadIdx.x;
    int f = tid & 63, sub = tid >> 6;
    int c = f >> 3, fl = f & 7;
    int flg = *flag;
    int base = blockIdx.x * 256 + sub * 64;
    float acc = 0.0f;
    int cur = -1, count = 0;
    for (int i = 0; i < 64; ++i) {
        int n = base + i;
        if (n >= NN) break;
        int g = flg ? braw[2 * n] : braw[n];
        if (g != cur) {
            if (cur >= 0) {
                atomicAdd(&pooled[cur * 64 + f], acc);
                if (f == 0) atomicAdd(&cnt[cur], (float)count);
            }
            cur = g; acc = 0.0f; count = 0;
        }
        acc += Hc[(size_t)c * CS + (size_t)n * 8 + fl];
        ++count;
    }
    if (cur >= 0) {
        atomicAdd(&pooled[cur * 64 + f], acc);
        if (f == 0) atomicAdd(&cnt[cur], (float)count);
    }
}

__global__ __launch_bounds__(512) void final_linear(
        const float* __restrict__ pooled, const float* __restrict__ cnt,
        const float* __restrict__ Wl, const float* __restrict__ bl,
        float* __restrict__ out) {
    int t = threadIdx.x;            // 512 = 256 graphs x 2 classes
    int b = t >> 1, c = t & 1;
    float inv = 1.0f / fmaxf(cnt[b], 1.0f);
    float acc = 0.0f;
#pragma unroll
    for (int fi = 0; fi < 64; ++fi)
        acc += pooled[b * 64 + fi] * Wl[fi * 2 + c];
    out[t] = acc * inv + bl[c];
}

// ---------------------------------------------------------------------------
static inline size_t align256(size_t x) { return (x + 255) & ~size_t(255); }

extern "C" void kernel_launch(void* const* d_in, const int* in_sizes, int n_in,
                              void* d_out, int out_size, void* d_ws, size_t ws_size,
                              hipStream_t stream) {
    const float* x   = (const float*)d_in[0];
    const int*  eraw = (const int*)d_in[1];
    const int*  braw = (const int*)d_in[2];
    const float* W1 = (const float*)d_in[3];
    const float* b1 = (const float*)d_in[4];
    const float* W2 = (const float*)d_in[5];
    const float* b2 = (const float*)d_in[6];
    const float* W3 = (const float*)d_in[7];
    const float* b3 = (const float*)d_in[8];
    const float* Wl = (const float*)d_in[9];
    const float* bl = (const float*)d_in[10];
    float* out = (float*)d_out;

    char* ws = (char*)d_ws;
    size_t off = 0;
    int*   flag   = (int*)(ws + off);   off = align256(off + 256);
    // contiguous zero region: degi, fillc, bfill, pooled, cnt
    size_t zoff = off;
    int*   degi   = (int*)(ws + off);   off = align256(off + (size_t)NN * 4);
    int*   fillc  = (int*)(ws + off);   off = align256(off + (size_t)NN * 4);
    int*   bfill  = (int*)(ws + off);   off = align256(off + 256);
    float* pooled = (float*)(ws + off); off = align256(off + (size_t)BB * HH * 4);
    float* cnt    = (float*)(ws + off); off = align256(off + (size_t)BB * 4);
    size_t zlen = off - zoff;
    float* dinv   = (float*)(ws + off); off = align256(off + (size_t)(NN + 1) * 4);
    int*   row2   = (int*)(ws + off);   off = align256(off + (size_t)(NN + 1) * 4);
    int*   bsum   = (int*)(ws + off);   off = align256(off + (size_t)NBLK * 4);
    ivec2* pairs  = (ivec2*)(ws + off); off = align256(off + (size_t)8 * CAP * 8);
    int*   esrc2  = (int*)(ws + off);   off = align256(off + ((size_t)EE + 16 * (size_t)NN + 256) * 4);
    float* bufA   = (float*)(ws + off); off = align256(off + (size_t)8 * CS * 4);
    float* bufB   = (float*)(ws + off); off = align256(off + (size_t)8 * CS * 4);

    detect_i64<<<1, 256, 0, stream>>>(eraw, flag);
    (void)hipMemsetAsync(ws + zoff, 0, zlen, stream);

    // padded CSR build: bucketize -> scan -> prefill -> L2-resident fill
    count_bucket<<<CB_BLK, 256, 0, stream>>>(eraw, flag, degi, bfill, pairs);
    scan1<<<NBLK, 256, 0, stream>>>(degi, row2, bsum, dinv);
    scan2<<<1, 512, 0, stream>>>(bsum);
    scan3<<<NBLK, 256, 0, stream>>>(row2, bsum);
    prefill_shard<<<8 * PRE_PER, 256, 0, stream>>>(row2, degi, esrc2);
    fill_shard2<<<8 * FSB_PER, 256, 0, stream>>>(pairs, bfill, row2, fillc, esrc2);

    // layer 1
    gemm_scaled<1><<<GEMM_BLK, 256, 0, stream>>>(x, W1, dinv, bufA);
    gather_ef<1><<<GATH_BLK, 256, 0, stream>>>(row2, esrc2, bufA, dinv, b1, bufB);
    // layer 2
    gemm_scaled<0><<<GEMM_BLK, 256, 0, stream>>>(bufB, W2, dinv, bufA);
    gather_ef<1><<<GATH_BLK, 256, 0, stream>>>(row2, esrc2, bufA, dinv, b2, bufB);
    // layer 3 (no relu)
    gemm_scaled<0><<<GEMM_BLK, 256, 0, stream>>>(bufB, W3, dinv, bufA);
    gather_ef<0><<<GATH_BLK, 256, 0, stream>>>(row2, esrc2, bufA, dinv, b3, bufB);

    // pool + classifier
    pool_kernel<<<NBLK, 256, 0, stream>>>(bufB, braw, flag, pooled, cnt);
    final_linear<<<1, 512, 0, stream>>>(pooled, cnt, Wl, bl, out);
}

// Round 11
// 432.267 us; speedup vs baseline: 1.4013x; 1.4013x over previous
//
#include <hip/hip_runtime.h>

#define NN 100000
#define EE 1250000
#define HH 64
#define BB 256
#define CC 2
#define NBLK 391                       // ceil((NN+1)/256)
#define CS4 ((size_t)(NN + 1) * 16)    // floats per 16-feature chunk (incl. dummy row NN)
#define NQ (NN / 4)                    // node-quads
#define GATH_BLK 8192
#define WPC4 ((GATH_BLK / 4) * 4)      // waves per chunk = 8192
#define GEMM_BLK 2048
#define GEMM_WAVES (GEMM_BLK * 4)
#define NSH 12500                      // nodes per XCD shard (NN/8)
#define CAP 170000                     // bucket capacity (expect 156250, sigma~370)
#define FSB_PER 128                    // fill blocks per shard
#define PRE_PER 49                     // prefill blocks per shard
#define CB_BLK ((EE + 1023) / 1024)    // count_bucket blocks (1024 edges each)

typedef int ivec4 __attribute__((ext_vector_type(4)));
typedef int ivec2 __attribute__((ext_vector_type(2)));

// ---------------------------------------------------------------------------
// Index dtype detection (int64 vs int32): int64 values < 2^31 -> odd words 0
// ---------------------------------------------------------------------------
__global__ void detect_i64(const int* __restrict__ raw, int* __restrict__ flag) {
    __shared__ int nonzero;
    if (threadIdx.x == 0) nonzero = 0;
    __syncthreads();
    int any = 0;
#pragma unroll
    for (int i = 0; i < 4; ++i) {
        int idx = 2 * (threadIdx.x + i * 256) + 1;
        if (raw[idx] != 0) any = 1;
    }
    if (any) atomicOr(&nonzero, 1);
    __syncthreads();
    if (threadIdx.x == 0) *flag = nonzero ? 0 : 1;   // 1 => int64
}

// ---------------------------------------------------------------------------
// Pass A: degree count + bucketize edges by dst-shard (8 buckets).
// ---------------------------------------------------------------------------
__global__ __launch_bounds__(256) void count_bucket(
        const int* __restrict__ raw, const int* __restrict__ flag,
        int* __restrict__ degi, int* __restrict__ bfill,
        ivec2* __restrict__ pairs) {
    __shared__ int lh[8];
    __shared__ int lbase[8];
    int tid = threadIdx.x;
    if (tid < 8) lh[tid] = 0;
    __syncthreads();
    int flg = *flag;
    int e0 = blockIdx.x * 1024 + tid;
    int sv[4], dv[4], rk[4], bk[4];
#pragma unroll
    for (int i = 0; i < 4; ++i) {
        int e = e0 + i * 256;
        if (e < EE) {
            int s = flg ? raw[2 * e]        : raw[e];
            int d = flg ? raw[2 * (EE + e)] : raw[EE + e];
            atomicAdd(&degi[d], 1);
            int b = d / NSH;               // const divide -> magic mul
            bk[i] = b;
            rk[i] = atomicAdd(&lh[b], 1);  // local rank (LDS atomic)
            sv[i] = s; dv[i] = d;
        } else {
            bk[i] = -1; sv[i] = 0; dv[i] = 0; rk[i] = 0;
        }
    }
    __syncthreads();
    if (tid < 8) lbase[tid] = atomicAdd(&bfill[tid], lh[tid]);
    __syncthreads();
#pragma unroll
    for (int i = 0; i < 4; ++i) {
        if (bk[i] >= 0) {
            int pos = bk[i] * CAP + lbase[bk[i]] + rk[i];
            ivec2 pr; pr.x = sv[i]; pr.y = dv[i];
            pairs[pos] = pr;
        }
    }
}

// scan over padded degrees pdeg = (deg+8)&~7 (self + dummies, mult of 8)
__global__ __launch_bounds__(256) void scan1(const int* __restrict__ degi,
                                             int* __restrict__ row2,
                                             int* __restrict__ bsum,
                                             float* __restrict__ dinv) {
    __shared__ int s[256];
    int tid = threadIdx.x;
    int n = blockIdx.x * 256 + tid;
    int dg = (n < NN) ? degi[n] : 0;
    int v = (n < NN) ? ((dg + 8) & ~7) : 0;   // pdeg (>= dg+1, mult 8)
    int x = v;
    s[tid] = x;
    __syncthreads();
    for (int off = 1; off < 256; off <<= 1) {
        int t = (tid >= off) ? s[tid - off] : 0;
        __syncthreads();
        x += t;
        s[tid] = x;
        __syncthreads();
    }
    if (n <= NN) row2[n] = x - v;            // exclusive (partial)
    if (n < NN) dinv[n] = rsqrtf((float)dg + 1.0f);
    if (tid == 255) bsum[blockIdx.x] = x;
}

__global__ __launch_bounds__(512) void scan2(int* __restrict__ bsum) {
    __shared__ int s[512];
    int tid = threadIdx.x;
    int v = (tid < NBLK) ? bsum[tid] : 0;
    int x = v;
    s[tid] = x;
    __syncthreads();
    for (int off = 1; off < 512; off <<= 1) {
        int t = (tid >= off) ? s[tid - off] : 0;
        __syncthreads();
        x += t;
        s[tid] = x;
        __syncthreads();
    }
    if (tid < NBLK) bsum[tid] = x - v;
}

__global__ void scan3(int* __restrict__ row2, const int* __restrict__ bsum) {
    int n = blockIdx.x * 256 + threadIdx.x;
    if (n <= NN) row2[n] += bsum[blockIdx.x];
}

// ---------------------------------------------------------------------------
// XCD-sharded prefill: self-slot + padding tail (up to 8 dummies)
// ---------------------------------------------------------------------------
__global__ void prefill_shard(const int* __restrict__ row2, const int* __restrict__ degi,
                              int* __restrict__ esrc2) {
    int shard = blockIdx.x & 7;
    int lb = blockIdx.x >> 3;
    int ln = lb * 256 + threadIdx.x;
    if (ln >= NSH) return;
    int n = shard * NSH + ln;
    int b = row2[n], e = row2[n + 1], dg = degi[n];
    esrc2[b] = n;                                  // self edge
    for (int k = b + 1 + dg; k < e; ++k) esrc2[k] = NN;  // padding -> zero row
}

// ---------------------------------------------------------------------------
// Pass B: per-shard counting-sort fill (bucket + window L2-resident per XCD)
// ---------------------------------------------------------------------------
__global__ __launch_bounds__(256) void fill_shard2(
        const ivec2* __restrict__ pairs, const int* __restrict__ bfill,
        const int* __restrict__ row2, int* __restrict__ fillc,
        int* __restrict__ esrc2) {
    int shard = blockIdx.x & 7;
    int lb = blockIdx.x >> 3;
    int tot = bfill[shard];
    const ivec2* __restrict__ bp = pairs + (size_t)shard * CAP;
    for (int i = lb * 256 + threadIdx.x; i < tot; i += FSB_PER * 256) {
        ivec2 p = bp[i];
        int pos = row2[p.y] + 1 + atomicAdd(&fillc[p.y], 1);
        esrc2[pos] = p.x;
    }
}

// ---------------------------------------------------------------------------
// G = dinv .* (X @ W), chunk-major out [4][NN+1][16]; row NN zeroed.
// One wave per row; uniform (scalar) X loads; W cols in VGPRs.
// ---------------------------------------------------------------------------
template <int IN_ROW>
__global__ __launch_bounds__(256) void gemm_scaled(
        const float* __restrict__ X, const float* __restrict__ W,
        const float* __restrict__ dinv, float* __restrict__ G) {
    int lane = threadIdx.x & 63;
    int gw = (blockIdx.x * 256 + threadIdx.x) >> 6;
    float Wreg[64];
#pragma unroll
    for (int k = 0; k < 64; ++k) Wreg[k] = W[k * 64 + lane];
    int c = lane >> 4, fl = lane & 15;
    for (int n = gw; n <= NN; n += GEMM_WAVES) {
        int nu = __builtin_amdgcn_readfirstlane(n);
        float r = 0.0f;
        if (nu < NN) {
            float a0 = 0.f, a1 = 0.f;
#pragma unroll
            for (int k = 0; k < 64; k += 2) {
                float x0, x1;
                if constexpr (IN_ROW) {
                    x0 = X[(size_t)nu * 64 + k];
                    x1 = X[(size_t)nu * 64 + k + 1];
                } else {
                    x0 = X[(size_t)(k >> 4) * CS4 + (size_t)nu * 16 + (k & 15)];
                    x1 = X[(size_t)((k + 1) >> 4) * CS4 + (size_t)nu * 16 + ((k + 1) & 15)];
                }
                a0 = fmaf(x0, Wreg[k], a0);
                a1 = fmaf(x1, Wreg[k + 1], a1);
            }
            r = (a0 + a1) * dinv[nu];
        }
        G[(size_t)c * CS4 + (size_t)nu * 16 + fl] = r;
    }
}

// ---------------------------------------------------------------------------
// C=4 gather, 4 nodes per wave: lane = node_sub(4) x feat(16).
// Per group-iteration: 2 int4 meta loads (1 tag each after dedup) + 8
// 64B G-row loads -> 8 independent chains in flight per lane. Each lane
// owns (node, feat): no cross-lane reduce. Padded mult-8 segments: no
// bounds checks; dummies hit the hot zeroed row NN.
// ---------------------------------------------------------------------------
template <int RELU>
__global__ __launch_bounds__(256) void gather16(
        const int* __restrict__ row2, const int* __restrict__ esrc2,
        const float* __restrict__ G, const float* __restrict__ dinv,
        const float* __restrict__ bias, float* __restrict__ Out) {
    int lane = threadIdx.x & 63;
    int fl = lane & 15, g = lane >> 4;
    int chunk = blockIdx.x & 3;            // blockIdx&7 -> XCD; &3 -> chunk (2 XCDs/chunk)
    int cidx = (blockIdx.x >> 3) * 2 + ((blockIdx.x & 7) >> 2);   // block idx within chunk
    int wv = (cidx << 2) + (threadIdx.x >> 6);
    const float* __restrict__ Gc = G + (size_t)chunk * CS4;
    float bv = bias[chunk * 16 + fl];

    for (int q = wv; q < NQ; q += WPC4) {
        int n = q * 4 + g;
        int beg = row2[n], end = row2[n + 1];
        float a0 = 0.f, a1 = 0.f;
        for (int j = beg; j < end; j += 8) {
            ivec4 mA = *reinterpret_cast<const ivec4*>(esrc2 + j);
            ivec4 mB = *reinterpret_cast<const ivec4*>(esrc2 + j + 4);
            float g0 = Gc[(unsigned)(mA.x * 16 + fl)];
            float g1 = Gc[(unsigned)(mA.y * 16 + fl)];
            float g2 = Gc[(unsigned)(mA.z * 16 + fl)];
            float g3 = Gc[(unsigned)(mA.w * 16 + fl)];
            float g4 = Gc[(unsigned)(mB.x * 16 + fl)];
            float g5 = Gc[(unsigned)(mB.y * 16 + fl)];
            float g6 = Gc[(unsigned)(mB.z * 16 + fl)];
            float g7 = Gc[(unsigned)(mB.w * 16 + fl)];
            a0 += (g0 + g2) + (g4 + g6);
            a1 += (g1 + g3) + (g5 + g7);
        }
        float o = fmaf(a0 + a1, dinv[n], bv);
        if constexpr (RELU) o = fmaxf(o, 0.f);
        Out[(size_t)chunk * CS4 + (size_t)q * 64 + lane] = o;   // 256B coalesced
    }
}

// ---------------------------------------------------------------------------
// Mean pool (batch sorted, chunk-major input) + final linear
// ---------------------------------------------------------------------------
__global__ __launch_bounds__(256) void pool_kernel(
        const float* __restrict__ Hc, const int* __restrict__ braw,
        const int* __restrict__ flag,
        float* __restrict__ pooled, float* __restrict__ cnt) {
    int tid = threadIdx.x;
    int f = tid & 63, sub = tid >> 6;
    int c = f >> 4, fl = f & 15;
    int flg = *flag;
    int base = blockIdx.x * 256 + sub * 64;
    float acc = 0.0f;
    int cur = -1, count = 0;
    for (int i = 0; i < 64; ++i) {
        int n = base + i;
        if (n >= NN) break;
        int g = flg ? braw[2 * n] : braw[n];
        if (g != cur) {
            if (cur >= 0) {
                atomicAdd(&pooled[cur * 64 + f], acc);
                if (f == 0) atomicAdd(&cnt[cur], (float)count);
            }
            cur = g; acc = 0.0f; count = 0;
        }
        acc += Hc[(size_t)c * CS4 + (size_t)n * 16 + fl];
        ++count;
    }
    if (cur >= 0) {
        atomicAdd(&pooled[cur * 64 + f], acc);
        if (f == 0) atomicAdd(&cnt[cur], (float)count);
    }
}

__global__ __launch_bounds__(512) void final_linear(
        const float* __restrict__ pooled, const float* __restrict__ cnt,
        const float* __restrict__ Wl, const float* __restrict__ bl,
        float* __restrict__ out) {
    int t = threadIdx.x;            // 512 = 256 graphs x 2 classes
    int b = t >> 1, c = t & 1;
    float inv = 1.0f / fmaxf(cnt[b], 1.0f);
    float acc = 0.0f;
#pragma unroll
    for (int fi = 0; fi < 64; ++fi)
        acc += pooled[b * 64 + fi] * Wl[fi * 2 + c];
    out[t] = acc * inv + bl[c];
}

// ---------------------------------------------------------------------------
static inline size_t align256(size_t x) { return (x + 255) & ~size_t(255); }

extern "C" void kernel_launch(void* const* d_in, const int* in_sizes, int n_in,
                              void* d_out, int out_size, void* d_ws, size_t ws_size,
                              hipStream_t stream) {
    const float* x   = (const float*)d_in[0];
    const int*  eraw = (const int*)d_in[1];
    const int*  braw = (const int*)d_in[2];
    const float* W1 = (const float*)d_in[3];
    const float* b1 = (const float*)d_in[4];
    const float* W2 = (const float*)d_in[5];
    const float* b2 = (const float*)d_in[6];
    const float* W3 = (const float*)d_in[7];
    const float* b3 = (const float*)d_in[8];
    const float* Wl = (const float*)d_in[9];
    const float* bl = (const float*)d_in[10];
    float* out = (float*)d_out;

    char* ws = (char*)d_ws;
    size_t off = 0;
    int*   flag   = (int*)(ws + off);   off = align256(off + 256);
    // contiguous zero region: degi, fillc, bfill, pooled, cnt
    size_t zoff = off;
    int*   degi   = (int*)(ws + off);   off = align256(off + (size_t)NN * 4);
    int*   fillc  = (int*)(ws + off);   off = align256(off + (size_t)NN * 4);
    int*   bfill  = (int*)(ws + off);   off = align256(off + 256);
    float* pooled = (float*)(ws + off); off = align256(off + (size_t)BB * HH * 4);
    float* cnt    = (float*)(ws + off); off = align256(off + (size_t)BB * 4);
    size_t zlen = off - zoff;
    float* dinv   = (float*)(ws + off); off = align256(off + (size_t)(NN + 1) * 4);
    int*   row2   = (int*)(ws + off);   off = align256(off + (size_t)(NN + 1) * 4);
    int*   bsum   = (int*)(ws + off);   off = align256(off + (size_t)NBLK * 4);
    ivec2* pairs  = (ivec2*)(ws + off); off = align256(off + (size_t)8 * CAP * 8);
    int*   esrc2  = (int*)(ws + off);   off = align256(off + ((size_t)EE + 8 * (size_t)NN + 256) * 4);
    float* bufA   = (float*)(ws + off); off = align256(off + (size_t)4 * CS4 * 4);
    float* bufB   = (float*)(ws + off); off = align256(off + (size_t)4 * CS4 * 4);

    detect_i64<<<1, 256, 0, stream>>>(eraw, flag);
    (void)hipMemsetAsync(ws + zoff, 0, zlen, stream);

    // padded CSR build: bucketize -> scan -> prefill -> L2-resident fill
    count_bucket<<<CB_BLK, 256, 0, stream>>>(eraw, flag, degi, bfill, pairs);
    scan1<<<NBLK, 256, 0, stream>>>(degi, row2, bsum, dinv);
    scan2<<<1, 512, 0, stream>>>(bsum);
    scan3<<<NBLK, 256, 0, stream>>>(row2, bsum);
    prefill_shard<<<8 * PRE_PER, 256, 0, stream>>>(row2, degi, esrc2);
    fill_shard2<<<8 * FSB_PER, 256, 0, stream>>>(pairs, bfill, row2, fillc, esrc2);

    // layer 1
    gemm_scaled<1><<<GEMM_BLK, 256, 0, stream>>>(x, W1, dinv, bufA);
    gather16<1><<<GATH_BLK, 256, 0, stream>>>(row2, esrc2, bufA, dinv, b1, bufB);
    // layer 2
    gemm_scaled<0><<<GEMM_BLK, 256, 0, stream>>>(bufB, W2, dinv, bufA);
    gather16<1><<<GATH_BLK, 256, 0, stream>>>(row2, esrc2, bufA, dinv, b2, bufB);
    // layer 3 (no relu)
    gemm_scaled<0><<<GEMM_BLK, 256, 0, stream>>>(bufB, W3, dinv, bufA);
    gather16<0><<<GATH_BLK, 256, 0, stream>>>(row2, esrc2, bufA, dinv, b3, bufB);

    // pool + classifier
    pool_kernel<<<NBLK, 256, 0, stream>>>(bufB, braw, flag, pooled, cnt);
    final_linear<<<1, 512, 0, stream>>>(pooled, cnt, Wl, bl, out);
}